// Round 7
// baseline (9510.394 us; speedup 1.0000x reference)
//
#include <hip/hip_runtime.h>
#include <stdint.h>

typedef short short8 __attribute__((ext_vector_type(8)));
typedef short short4v __attribute__((ext_vector_type(4)));
typedef float floatx4 __attribute__((ext_vector_type(4)));

#define LOG2E 1.44269504088896340736f

__device__ __forceinline__ float bf2f(unsigned short u) {
  unsigned v = ((unsigned)u) << 16;
  return __builtin_bit_cast(float, v);
}
__device__ __forceinline__ unsigned short f2bf(float f) {
  unsigned v = __builtin_bit_cast(unsigned, f);
  v += 0x7FFFu + ((v >> 16) & 1u);   // RNE
  return (unsigned short)(v >> 16);
}
__device__ __forceinline__ float fast_exp2(float x) {
#if __has_builtin(__builtin_amdgcn_exp2f)
  return __builtin_amdgcn_exp2f(x);
#else
  return exp2f(x);
#endif
}
__device__ __forceinline__ float fast_rcp(float x) {
#if __has_builtin(__builtin_amdgcn_rcpf)
  return __builtin_amdgcn_rcpf(x);
#else
  return 1.0f / x;
#endif
}
__device__ __forceinline__ float fsig(float x) {
  return fast_rcp(1.0f + fast_exp2(-LOG2E * x));
}
__device__ __forceinline__ floatx4 mfma16(short8 a, short8 b, floatx4 c) {
  return __builtin_amdgcn_mfma_f32_16x16x32_bf16(a, b, c, 0, 0, 0);
}

// ---------------------------------------------------------------------------
// Dtype detection: if the buffer is float32, even-indexed u16 halves are float
// mantissa bits -> ~6% have bf16-exponent >= 0xF0. If bf16 (0.05-scaled
// weights), exponent <= 125 always -> 0 hits. flag: 1 = f32, 0 = bf16.
// ---------------------------------------------------------------------------
__global__ __launch_bounds__(256) void detect_kernel(
    const unsigned short* __restrict__ w, int n_u16, int* __restrict__ flag)
{
  __shared__ int cnt;
  if (threadIdx.x == 0) cnt = 0;
  __syncthreads();
  int local = 0;
  for (int i = threadIdx.x * 2; i < n_u16; i += 512) {  // even indices only
    unsigned e = (w[i] >> 7) & 0xFF;
    if (e >= 0xF0) local++;
  }
  atomicAdd(&cnt, local);
  __syncthreads();
  if (threadIdx.x == 0) *flag = (cnt > 64) ? 1 : 0;
}

// ---------------------------------------------------------------------------
// One merged kernel canonicalizing all 14 weight tensors to bf16 in ws.
// Grid: 614 blocks x 256 threads, 1024 elements per block.
// ---------------------------------------------------------------------------
__global__ __launch_bounds__(256) void convertw_kernel(
    const void* s0, const void* s1, const void* s2, const void* s3,
    const void* s4, const void* s5, const void* s6, const void* s7,
    const void* s8, const void* s9, const void* s10, const void* s11,
    const void* s12, const void* s13,
    unsigned short* __restrict__ wbuf, const int* __restrict__ flag)
{
  const void* srcs[14] = {s0, s1, s2, s3, s4, s5, s6, s7, s8, s9, s10, s11, s12, s13};
  const int woff[14] = {0,      49152,  114688, 115200, 164352, 229888,
                        230400, 361472, 427008, 427520, 558592, 624128,
                        624640, 624896};
  const int wlen[14] = {49152, 65536, 512, 49152, 65536, 512,
                        131072, 65536, 512, 131072, 65536, 512, 256, 1};
  int sb = 0, i = 0;
  for (i = 0; i < 14; ++i) {
    int nb = (wlen[i] + 1023) >> 10;
    if ((int)blockIdx.x < sb + nb) break;
    sb += nb;
  }
  const int base = ((int)blockIdx.x - sb) * 1024 + (int)threadIdx.x * 4;
  unsigned short* dst = wbuf + woff[i];
  if (*flag) {
    const float* s = (const float*)srcs[i];
#pragma unroll
    for (int j = 0; j < 4; ++j)
      if (base + j < wlen[i]) dst[base + j] = f2bf(s[base + j]);
  } else {
    const unsigned short* s = (const unsigned short*)srcs[i];
#pragma unroll
    for (int j = 0; j < 4; ++j)
      if (base + j < wlen[i]) dst[base + j] = s[base + j];
  }
}

// ---------------------------------------------------------------------------
// Fused recurrent kernel. Two layer contexts (a = layer L0 chunk c,
// b = layer L1 chunk c-1); blocks 0..7 -> ctx a, 8..15 -> ctx b.
// Within a context: block = dir*4 + batch-group (16 batch rows each).
// Z fp32 [steps][1024][64] (col = dir*512 + gate*128 + unit, batch fastest).
// Z(t+1) prefetched at TOP of step t, pinned with sched_barrier(0).
// Pointwise uses fused sig*tanh rational forms: 5 exp + 3 rcp per (b,u) pair.
// ---------------------------------------------------------------------------
__global__ __launch_bounds__(512, 2) void rec_kernel(
    const float* __restrict__ Za, const unsigned short* __restrict__ whhfa,
    const unsigned short* __restrict__ whhba,
    unsigned short* __restrict__ ysa, float* __restrict__ ca,
    unsigned short* __restrict__ ha, int inita,
    const float* __restrict__ Zb, const unsigned short* __restrict__ whhfb,
    const unsigned short* __restrict__ whhbb,
    unsigned short* __restrict__ ysb, float* __restrict__ cb,
    unsigned short* __restrict__ hb, int initb,
    int steps)
{
  __shared__ __align__(16) unsigned short hbuf[2][16][136];
  const int blk = blockIdx.x;
  const float* Z;
  const unsigned short* whhF;
  const unsigned short* whhB;
  unsigned short* ys;
  float* cst;
  unsigned short* hst;
  int init;
  if (blk < 8) {
    Z = Za; whhF = whhfa; whhB = whhba; ys = ysa; cst = ca; hst = ha; init = inita;
  } else {
    Z = Zb; whhF = whhfb; whhB = whhbb; ys = ysb; cst = cb; hst = hb; init = initb;
  }
  const int d = (blk >> 2) & 1, bg = blk & 3;
  const unsigned short* whh = d ? whhB : whhF;

  const int tid = threadIdx.x;
  const int w = tid >> 6, lane = tid & 63, q = lane >> 4, cc = lane & 15;
  const int u = w * 16 + cc;

  // Whh as MFMA B-fragments, register-resident (64 regs).
  short8 bfrag[4][4];
#pragma unroll
  for (int g = 0; g < 4; ++g)
#pragma unroll
    for (int k = 0; k < 4; ++k)
      bfrag[g][k] = *(const short8*)(whh + (size_t)(g * 128 + u) * 128 + k * 32 + q * 8);

  float creg[4];
  const int row = tid >> 5;          // 0..15
  const int col4 = (tid & 31) * 4;   // 0..124
  if (init) {
#pragma unroll
    for (int r = 0; r < 4; ++r) creg[r] = 0.f;
    short4v zz = {0, 0, 0, 0};
    *(short4v*)&hbuf[0][row][col4] = zz;
  } else {
#pragma unroll
    for (int r = 0; r < 4; ++r)
      creg[r] = cst[(size_t)(d * 64 + bg * 16 + q * 4 + r) * 128 + u];
    *(short4v*)&hbuf[0][row][col4] =
        *(const short4v*)(hst + (size_t)(d * 64 + bg * 16 + row) * 128 + col4);
  }
  __syncthreads();

  const int zlane = (d * 512 + u) * 64 + bg * 16 + q * 4;
  // prime: Z(0)
  floatx4 zcur[4];
#pragma unroll
  for (int g = 0; g < 4; ++g)
    zcur[g] = *(const floatx4*)(Z + zlane + g * 8192);

  for (int t = 0; t < steps; ++t) {
    const int cur = t & 1, nxt = cur ^ 1;
    // prefetch Z(t+1) FIRST (clamp is scalar: SALU-only), pinned
    const int tn = (t + 1 < steps) ? t + 1 : t;
    const float* ztn = Z + (size_t)tn * 65536 + zlane;
    floatx4 zpf[4];
#pragma unroll
    for (int g = 0; g < 4; ++g)
      zpf[g] = *(const floatx4*)(ztn + g * 8192);
    __builtin_amdgcn_sched_barrier(0);

    floatx4 acc[4];
#pragma unroll
    for (int g = 0; g < 4; ++g) acc[g] = zcur[g];

    short8 af[4];
#pragma unroll
    for (int k = 0; k < 4; ++k)
      af[k] = *(const short8*)&hbuf[cur][cc][k * 32 + q * 8];
#pragma unroll
    for (int g = 0; g < 4; ++g)
#pragma unroll
      for (int k = 0; k < 4; ++k)
        acc[g] = mfma16(af[k], bfrag[g][k], acc[g]);

    // fused LSTM pointwise: lane owns (b = bg*16 + q*4 + r, unit u)
    // sig(i)*tanh(g) = ei*(eg-1) / ((1+ei)*(1+eg)),  eg = e^{2 zg}
#pragma unroll
    for (int r = 0; r < 4; ++r) {
      float zi = acc[0][r], zf = acc[1][r], zg = acc[2][r], zo = acc[3][r];
      float ei = fast_exp2(LOG2E * zi);
      float eg = fast_exp2((2.0f * LOG2E) * zg);
      float ef = fast_exp2(LOG2E * zf);
      float it = ei * (eg - 1.0f) * fast_rcp((1.0f + ei) * (1.0f + eg));
      float sf = ef * fast_rcp(1.0f + ef);
      float cn = sf * creg[r] + it;
      creg[r] = cn;
      float eo = fast_exp2(LOG2E * zo);
      float ec = fast_exp2(fminf((2.0f * LOG2E) * cn, 88.0f));  // c can grow
      float h = eo * (ec - 1.0f) * fast_rcp((1.0f + eo) * (1.0f + ec));
      hbuf[nxt][q * 4 + r][u] = f2bf(h);
    }
    __syncthreads();
    unsigned short* yd = ys + (size_t)(t * 64 + bg * 16 + row) * 256 + d * 128 + col4;
    *(short4v*)yd = *(const short4v*)&hbuf[nxt][row][col4];
#pragma unroll
    for (int g = 0; g < 4; ++g) zcur[g] = zpf[g];
  }
#pragma unroll
  for (int r = 0; r < 4; ++r)
    cst[(size_t)(d * 64 + bg * 16 + q * 4 + r) * 128 + u] = creg[r];
  const int fin = steps & 1;
  *(short4v*)(hst + (size_t)(d * 64 + bg * 16 + row) * 128 + col4) =
      *(const short4v*)&hbuf[fin][row][col4];
}

// ---------------------------------------------------------------------------
// Input GEMM: Z[t][col][b] = sum_k A[t*64+b][k]*Wih[col][k] + bias[col]
// A may be raw f32/bf16 input (dyn=1: dtype from *flag, converted during
// staging) or internal bf16 (dyn=0). Z output fp32.
// ---------------------------------------------------------------------------
template <int K>
__global__ __launch_bounds__(256, 4) void gemm_kernel(
    const void* __restrict__ A, size_t a_off, int dyn,
    const int* __restrict__ flag,
    const unsigned short* __restrict__ Bf,   // [512][K]
    const unsigned short* __restrict__ Bb,
    const unsigned short* __restrict__ biasf,  // [512]
    const unsigned short* __restrict__ biasb,
    float* __restrict__ Z)                   // [C][1024][64] fp32
{
  constexpr int RS = K + 8;
  __shared__ __align__(16) unsigned short As[64 * RS];
  const int t = blockIdx.x, ns = blockIdx.y;
  const int tid = threadIdx.x, w = tid >> 6, lane = tid & 63;
  const int q = lane >> 4, cc = lane & 15;
  constexpr int K8 = K / 8;
  const int use32 = dyn ? *flag : 0;   // wave-uniform branch
  if (use32) {
    const float* Arow = (const float*)A + a_off + (size_t)t * 64 * K;
    for (int ci = tid; ci < 64 * K8; ci += 256) {
      int r_ = ci / K8, c8 = ci % K8;
      const float* p = Arow + r_ * K + c8 * 8;
      floatx4 x0 = *(const floatx4*)p;
      floatx4 x1 = *(const floatx4*)(p + 4);
      short8 s;
#pragma unroll
      for (int j = 0; j < 4; ++j) {
        s[j] = (short)f2bf(x0[j]);
        s[4 + j] = (short)f2bf(x1[j]);
      }
      *(short8*)&As[r_ * RS + c8 * 8] = s;
    }
  } else {
    const unsigned short* Arow = (const unsigned short*)A + a_off + (size_t)t * 64 * K;
    for (int ci = tid; ci < 64 * K8; ci += 256) {
      int r_ = ci / K8, c8 = ci % K8;
      *(short8*)&As[r_ * RS + c8 * 8] = *(const short8*)&Arow[r_ * K + c8 * 8];
    }
  }
  __syncthreads();
  const int colbase = ns * 256 + w * 64;
  const unsigned short* Bp    = (colbase < 512) ? Bf : Bb;
  const unsigned short* biasp = (colbase < 512) ? biasf : biasb;
  const int cb = (colbase < 512) ? colbase : colbase - 512;
  floatx4 acc[4][4];
#pragma unroll
  for (int m = 0; m < 4; ++m)
#pragma unroll
    for (int n = 0; n < 4; ++n)
#pragma unroll
      for (int r = 0; r < 4; ++r) acc[m][n][r] = 0.f;
#pragma unroll
  for (int ks = 0; ks < K / 32; ++ks) {
    short8 af[4], bfr[4];
#pragma unroll
    for (int m = 0; m < 4; ++m)
      af[m] = *(const short8*)&As[(m * 16 + cc) * RS + ks * 32 + q * 8];
#pragma unroll
    for (int n = 0; n < 4; ++n)
      bfr[n] = *(const short8*)&Bp[(size_t)(cb + n * 16 + cc) * K + ks * 32 + q * 8];
#pragma unroll
    for (int m = 0; m < 4; ++m)
#pragma unroll
      for (int n = 0; n < 4; ++n)
        acc[m][n] = mfma16(af[m], bfr[n], acc[m][n]);
  }
#pragma unroll
  for (int n = 0; n < 4; ++n) {
    const int col = colbase + n * 16 + cc;
    const float bv = bf2f(biasp[cb + n * 16 + cc]);
#pragma unroll
    for (int m = 0; m < 4; ++m) {
      floatx4 v = acc[m][n];
      v += bv;
      *(floatx4*)&Z[(size_t)(t * 1024 + col) * 64 + m * 16 + q * 4] = v;
    }
  }
}

// ---------------------------------------------------------------------------
// FC head: one wave per (t,b). Output dtype via flag (1 = f32, 0 = bf16).
// ---------------------------------------------------------------------------
__global__ __launch_bounds__(256) void fc_kernel(
    const unsigned short* __restrict__ ys,   // [n][256] bf16
    const unsigned short* __restrict__ fcw,  // [256]
    const unsigned short* __restrict__ fcb,  // [1]
    void* __restrict__ out, size_t out_off, int n,
    const int* __restrict__ flag)
{
  const int gw = (int)((blockIdx.x * 256 + threadIdx.x) >> 6);
  const int lane = threadIdx.x & 63;
  if (gw >= n) return;
  const unsigned short* rp = ys + (size_t)gw * 256 + lane * 4;
  float s = 0.f;
#pragma unroll
  for (int i = 0; i < 4; ++i) s += bf2f(rp[i]) * bf2f(fcw[lane * 4 + i]);
#pragma unroll
  for (int m = 32; m >= 1; m >>= 1) s += __shfl_xor(s, m, 64);
  if (lane == 0) {
    const float v = fsig(s + bf2f(fcb[0]));
    if (*flag) ((float*)out)[out_off + gw] = v;
    else       ((unsigned short*)out)[out_off + gw] = f2bf(v);
  }
}

extern "C" void kernel_launch(void* const* d_in, const int* in_sizes, int n_in,
                              void* d_out, int out_size, void* d_ws, size_t ws_size,
                              hipStream_t stream)
{
  (void)in_sizes; (void)n_in; (void)out_size;
  const int S = 4096;

  int* flag = (int*)d_ws;
  unsigned short* wbuf = (unsigned short*)((char*)d_ws + 256);
  static const int woff[14] = {0,      49152,  114688, 115200, 164352, 229888,
                               230400, 361472, 427008, 427520, 558592, 624128,
                               624640, 624896};
  const size_t wbuf_end = 256 + 1250304;  // bytes

  // Per-step bytes: Z0+Z1 fp32 2*262144 + ys0+ys1 2*32768 = 589824.
  // Fixed: wbuf_end + state 196608.
  int C = 1;
  for (int cand = 512; cand >= 1; cand >>= 1) {
    size_t need = (size_t)cand * 589824 + wbuf_end + 196608;
    if (need <= ws_size) { C = cand; break; }
  }
  float* Z0 = (float*)((char*)d_ws + wbuf_end);       // C*65536 f32
  float* Z1 = Z0 + (size_t)C * 65536;
  unsigned short* ys0 = (unsigned short*)(Z1 + (size_t)C * 65536);  // C*16384 u16
  unsigned short* ys1 = ys0 + (size_t)C * 16384;
  float* c0 = (float*)(ys1 + (size_t)C * 16384);
  float* c1 = c0 + 16384;
  unsigned short* h0 = (unsigned short*)(c1 + 16384);
  unsigned short* h1 = h0 + 16384;

  const unsigned short* wih0f = wbuf + woff[0];
  const unsigned short* whh0f = wbuf + woff[1];
  const unsigned short* b0f   = wbuf + woff[2];
  const unsigned short* wih0b = wbuf + woff[3];
  const unsigned short* whh0b = wbuf + woff[4];
  const unsigned short* b0b   = wbuf + woff[5];
  const unsigned short* wih1f = wbuf + woff[6];
  const unsigned short* whh1f = wbuf + woff[7];
  const unsigned short* b1f   = wbuf + woff[8];
  const unsigned short* wih1b = wbuf + woff[9];
  const unsigned short* whh1b = wbuf + woff[10];
  const unsigned short* b1b   = wbuf + woff[11];
  const unsigned short* fcw   = wbuf + woff[12];
  const unsigned short* fcb   = wbuf + woff[13];

  detect_kernel<<<1, 256, 0, stream>>>((const unsigned short*)d_in[1], 49152, flag);
  convertw_kernel<<<614, 256, 0, stream>>>(
      d_in[1], d_in[2], d_in[3], d_in[4], d_in[5], d_in[6], d_in[7],
      d_in[8], d_in[9], d_in[10], d_in[11], d_in[12], d_in[13], d_in[14],
      wbuf, flag);

  const int nc = S / C;

  // prologue: chunk 0, layer 0
  gemm_kernel<96><<<dim3(C, 4), 256, 0, stream>>>(
      d_in[0], 0, 1, flag, wih0f, wih0b, b0f, b0b, Z0);
  rec_kernel<<<8, 512, 0, stream>>>(Z0, whh0f, whh0b, ys0, c0, h0, 1,
                                    Z0, whh0f, whh0b, ys0, c0, h0, 1, C);
  // pipelined middle: layer0 chunk c fused with layer1 chunk c-1
  for (int c = 1; c < nc; ++c) {
    gemm_kernel<96><<<dim3(C, 4), 256, 0, stream>>>(
        d_in[0], (size_t)c * C * 6144, 1, flag, wih0f, wih0b, b0f, b0b, Z0);
    gemm_kernel<256><<<dim3(C, 4), 256, 0, stream>>>(
        ys0, 0, 0, flag, wih1f, wih1b, b1f, b1b, Z1);
    rec_kernel<<<16, 512, 0, stream>>>(Z0, whh0f, whh0b, ys0, c0, h0, 0,
                                       Z1, whh1f, whh1b, ys1, c1, h1, (c == 1) ? 1 : 0, C);
    fc_kernel<<<C * 16, 256, 0, stream>>>(ys1, fcw, fcb, d_out,
                                          (size_t)(c - 1) * C * 64, C * 64, flag);
  }
  // epilogue: layer1 chunk nc-1
  gemm_kernel<256><<<dim3(C, 4), 256, 0, stream>>>(
      ys0, 0, 0, flag, wih1f, wih1b, b1f, b1b, Z1);
  rec_kernel<<<8, 512, 0, stream>>>(Z1, whh1f, whh1b, ys1, c1, h1, (nc == 1) ? 1 : 0,
                                    Z1, whh1f, whh1b, ys1, c1, h1, (nc == 1) ? 1 : 0, C);
  fc_kernel<<<C * 16, 256, 0, stream>>>(ys1, fcw, fcb, d_out,
                                        (size_t)(nc - 1) * C * 64, C * 64, flag);
}

// Round 8
// 8030.648 us; speedup vs baseline: 1.1843x; 1.1843x over previous
//
#include <hip/hip_runtime.h>
#include <stdint.h>

typedef short short8 __attribute__((ext_vector_type(8)));
typedef short short4v __attribute__((ext_vector_type(4)));
typedef float floatx4 __attribute__((ext_vector_type(4)));

#define LOG2E 1.44269504088896340736f

__device__ __forceinline__ float bf2f(unsigned short u) {
  unsigned v = ((unsigned)u) << 16;
  return __builtin_bit_cast(float, v);
}
__device__ __forceinline__ unsigned short f2bf(float f) {
  unsigned v = __builtin_bit_cast(unsigned, f);
  v += 0x7FFFu + ((v >> 16) & 1u);   // RNE
  return (unsigned short)(v >> 16);
}
__device__ __forceinline__ float fast_exp2(float x) {
#if __has_builtin(__builtin_amdgcn_exp2f)
  return __builtin_amdgcn_exp2f(x);
#else
  return exp2f(x);
#endif
}
__device__ __forceinline__ float fast_rcp(float x) {
#if __has_builtin(__builtin_amdgcn_rcpf)
  return __builtin_amdgcn_rcpf(x);
#else
  return 1.0f / x;
#endif
}
__device__ __forceinline__ float fsig(float x) {
  return fast_rcp(1.0f + fast_exp2(-LOG2E * x));
}
__device__ __forceinline__ float ftanh(float x) {
  float e = fast_exp2(2.0f * LOG2E * x);
  return 1.0f - 2.0f * fast_rcp(e + 1.0f);
}
__device__ __forceinline__ floatx4 mfma16(short8 a, short8 b, floatx4 c) {
  return __builtin_amdgcn_mfma_f32_16x16x32_bf16(a, b, c, 0, 0, 0);
}

// ---------------------------------------------------------------------------
// Dtype detection: if the buffer is float32, even-indexed u16 halves are float
// mantissa bits -> ~6% have bf16-exponent >= 0xF0. If bf16 (0.05-scaled
// weights), exponent <= 125 always -> 0 hits. flag: 1 = f32, 0 = bf16.
// ---------------------------------------------------------------------------
__global__ __launch_bounds__(256) void detect_kernel(
    const unsigned short* __restrict__ w, int n_u16, int* __restrict__ flag)
{
  __shared__ int cnt;
  if (threadIdx.x == 0) cnt = 0;
  __syncthreads();
  int local = 0;
  for (int i = threadIdx.x * 2; i < n_u16; i += 512) {  // even indices only
    unsigned e = (w[i] >> 7) & 0xFF;
    if (e >= 0xF0) local++;
  }
  atomicAdd(&cnt, local);
  __syncthreads();
  if (threadIdx.x == 0) *flag = (cnt > 64) ? 1 : 0;
}

// ---------------------------------------------------------------------------
// One merged kernel canonicalizing all 14 weight tensors to bf16 in ws.
// Grid: 614 blocks x 256 threads, 1024 elements per block.
// ---------------------------------------------------------------------------
__global__ __launch_bounds__(256) void convertw_kernel(
    const void* s0, const void* s1, const void* s2, const void* s3,
    const void* s4, const void* s5, const void* s6, const void* s7,
    const void* s8, const void* s9, const void* s10, const void* s11,
    const void* s12, const void* s13,
    unsigned short* __restrict__ wbuf, const int* __restrict__ flag)
{
  const void* srcs[14] = {s0, s1, s2, s3, s4, s5, s6, s7, s8, s9, s10, s11, s12, s13};
  const int woff[14] = {0,      49152,  114688, 115200, 164352, 229888,
                        230400, 361472, 427008, 427520, 558592, 624128,
                        624640, 624896};
  const int wlen[14] = {49152, 65536, 512, 49152, 65536, 512,
                        131072, 65536, 512, 131072, 65536, 512, 256, 1};
  int sb = 0, i = 0;
  for (i = 0; i < 14; ++i) {
    int nb = (wlen[i] + 1023) >> 10;
    if ((int)blockIdx.x < sb + nb) break;
    sb += nb;
  }
  const int base = ((int)blockIdx.x - sb) * 1024 + (int)threadIdx.x * 4;
  unsigned short* dst = wbuf + woff[i];
  if (*flag) {
    const float* s = (const float*)srcs[i];
#pragma unroll
    for (int j = 0; j < 4; ++j)
      if (base + j < wlen[i]) dst[base + j] = f2bf(s[base + j]);
  } else {
    const unsigned short* s = (const unsigned short*)srcs[i];
#pragma unroll
    for (int j = 0; j < 4; ++j)
      if (base + j < wlen[i]) dst[base + j] = s[base + j];
  }
}

// ---------------------------------------------------------------------------
// Fused recurrent kernel (round-6 proven body + LDS-only in-loop barrier).
// Two layer contexts (a = L0 chunk c, b = L1 chunk c-1); blocks 0..7 -> a,
// 8..15 -> b. Within a context: block = dir*4 + batch-group (16 rows).
// Z bf16 [steps][1024][64] (col = dir*512 + gate*128 + unit, batch fastest).
// Z(t+1) prefetched at TOP of step t (pinned by sched_barrier). The in-loop
// barrier waits lgkmcnt(0) ONLY: hbuf double-buffer needs LDS visibility, the
// ys store ack and Z prefetch do NOT need draining (dep-tracked vmcnt at use).
// ---------------------------------------------------------------------------
__global__ __launch_bounds__(512, 2) void rec_kernel(
    const unsigned short* __restrict__ Za, const unsigned short* __restrict__ whhfa,
    const unsigned short* __restrict__ whhba,
    unsigned short* __restrict__ ysa, float* __restrict__ ca,
    unsigned short* __restrict__ ha, int inita,
    const unsigned short* __restrict__ Zb, const unsigned short* __restrict__ whhfb,
    const unsigned short* __restrict__ whhbb,
    unsigned short* __restrict__ ysb, float* __restrict__ cb,
    unsigned short* __restrict__ hb, int initb,
    int steps)
{
  __shared__ __align__(16) unsigned short hbuf[2][16][136];
  const int blk = blockIdx.x;
  const unsigned short* Z;
  const unsigned short* whhF;
  const unsigned short* whhB;
  unsigned short* ys;
  float* cst;
  unsigned short* hst;
  int init;
  if (blk < 8) {
    Z = Za; whhF = whhfa; whhB = whhba; ys = ysa; cst = ca; hst = ha; init = inita;
  } else {
    Z = Zb; whhF = whhfb; whhB = whhbb; ys = ysb; cst = cb; hst = hb; init = initb;
  }
  const int d = (blk >> 2) & 1, bg = blk & 3;
  const unsigned short* whh = d ? whhB : whhF;

  const int tid = threadIdx.x;
  const int w = tid >> 6, lane = tid & 63, q = lane >> 4, cc = lane & 15;
  const int u = w * 16 + cc;

  // Whh as MFMA B-fragments, register-resident (64 regs).
  short8 bfrag[4][4];
#pragma unroll
  for (int g = 0; g < 4; ++g)
#pragma unroll
    for (int k = 0; k < 4; ++k)
      bfrag[g][k] = *(const short8*)(whh + (size_t)(g * 128 + u) * 128 + k * 32 + q * 8);

  float creg[4];
  const int row = tid >> 5;          // 0..15
  const int col4 = (tid & 31) * 4;   // 0..124
  if (init) {
#pragma unroll
    for (int r = 0; r < 4; ++r) creg[r] = 0.f;
    short4v zz = {0, 0, 0, 0};
    *(short4v*)&hbuf[0][row][col4] = zz;
  } else {
#pragma unroll
    for (int r = 0; r < 4; ++r)
      creg[r] = cst[(size_t)(d * 64 + bg * 16 + q * 4 + r) * 128 + u];
    *(short4v*)&hbuf[0][row][col4] =
        *(const short4v*)(hst + (size_t)(d * 64 + bg * 16 + row) * 128 + col4);
  }
  __syncthreads();

  const int zlane = (d * 512 + u) * 64 + bg * 16 + q * 4;
  // prime: Z(0) in bf16
  short4v zcur[4];
#pragma unroll
  for (int g = 0; g < 4; ++g)
    zcur[g] = *(const short4v*)(Z + zlane + g * 8192);

  for (int t = 0; t < steps; ++t) {
    const int cur = t & 1, nxt = cur ^ 1;
    // issue prefetch of Z(t+1) FIRST, pinned by a scheduling barrier
    const int tn = (t + 1 < steps) ? t + 1 : t;
    const unsigned short* ztn = Z + (size_t)tn * 65536 + zlane;
    short4v zpf[4];
#pragma unroll
    for (int g = 0; g < 4; ++g)
      zpf[g] = *(const short4v*)(ztn + g * 8192);
    __builtin_amdgcn_sched_barrier(0);

    // convert current z (bf16 -> fp32) into C-layout accumulators
    floatx4 acc[4];
#pragma unroll
    for (int g = 0; g < 4; ++g)
#pragma unroll
      for (int r = 0; r < 4; ++r)
        acc[g][r] = bf2f((unsigned short)zcur[g][r]);

    short8 af[4];
#pragma unroll
    for (int k = 0; k < 4; ++k)
      af[k] = *(const short8*)&hbuf[cur][cc][k * 32 + q * 8];
#pragma unroll
    for (int g = 0; g < 4; ++g)
#pragma unroll
      for (int k = 0; k < 4; ++k)
        acc[g] = mfma16(af[k], bfrag[g][k], acc[g]);
    // pointwise: lane owns (batch bg*16 + q*4+r, unit u), gates local
#pragma unroll
    for (int r = 0; r < 4; ++r) {
      float zi = acc[0][r], zf = acc[1][r], zg = acc[2][r], zo = acc[3][r];
      float cn = fsig(zf) * creg[r] + fsig(zi) * ftanh(zg);
      creg[r] = cn;
      hbuf[nxt][q * 4 + r][u] = f2bf(fsig(zo) * ftanh(cn));
    }
    // LDS-only barrier: drain ds ops, leave vmcnt (ys store + Z prefetch) alone
    asm volatile("s_waitcnt lgkmcnt(0)\n\ts_barrier" ::: "memory");
    unsigned short* yd = ys + (size_t)(t * 64 + bg * 16 + row) * 256 + d * 128 + col4;
    *(short4v*)yd = *(const short4v*)&hbuf[nxt][row][col4];
#pragma unroll
    for (int g = 0; g < 4; ++g) zcur[g] = zpf[g];
  }
#pragma unroll
  for (int r = 0; r < 4; ++r)
    cst[(size_t)(d * 64 + bg * 16 + q * 4 + r) * 128 + u] = creg[r];
  const int fin = steps & 1;
  *(short4v*)(hst + (size_t)(d * 64 + bg * 16 + row) * 128 + col4) =
      *(const short4v*)&hbuf[fin][row][col4];
}

// ---------------------------------------------------------------------------
// Input GEMM: Z[t][col][b] = sum_k A[t*64+b][k]*Wih[col][k] + bias[col]
// A may be raw f32/bf16 input (dyn=1: dtype from *flag, converted during
// staging) or internal bf16 (dyn=0). Z output bf16.
// ---------------------------------------------------------------------------
template <int K>
__global__ __launch_bounds__(256, 4) void gemm_kernel(
    const void* __restrict__ A, size_t a_off, int dyn,
    const int* __restrict__ flag,
    const unsigned short* __restrict__ Bf,   // [512][K]
    const unsigned short* __restrict__ Bb,
    const unsigned short* __restrict__ biasf,  // [512]
    const unsigned short* __restrict__ biasb,
    unsigned short* __restrict__ Z)          // [C][1024][64] bf16
{
  constexpr int RS = K + 8;
  __shared__ __align__(16) unsigned short As[64 * RS];
  const int t = blockIdx.x, ns = blockIdx.y;
  const int tid = threadIdx.x, w = tid >> 6, lane = tid & 63;
  const int q = lane >> 4, cc = lane & 15;
  constexpr int K8 = K / 8;
  const int use32 = dyn ? *flag : 0;   // wave-uniform branch
  if (use32) {
    const float* Arow = (const float*)A + a_off + (size_t)t * 64 * K;
    for (int ci = tid; ci < 64 * K8; ci += 256) {
      int r_ = ci / K8, c8 = ci % K8;
      const float* p = Arow + r_ * K + c8 * 8;
      floatx4 x0 = *(const floatx4*)p;
      floatx4 x1 = *(const floatx4*)(p + 4);
      short8 s;
#pragma unroll
      for (int j = 0; j < 4; ++j) {
        s[j] = (short)f2bf(x0[j]);
        s[4 + j] = (short)f2bf(x1[j]);
      }
      *(short8*)&As[r_ * RS + c8 * 8] = s;
    }
  } else {
    const unsigned short* Arow = (const unsigned short*)A + a_off + (size_t)t * 64 * K;
    for (int ci = tid; ci < 64 * K8; ci += 256) {
      int r_ = ci / K8, c8 = ci % K8;
      *(short8*)&As[r_ * RS + c8 * 8] = *(const short8*)&Arow[r_ * K + c8 * 8];
    }
  }
  __syncthreads();
  const int colbase = ns * 256 + w * 64;
  const unsigned short* Bp    = (colbase < 512) ? Bf : Bb;
  const unsigned short* biasp = (colbase < 512) ? biasf : biasb;
  const int cb = (colbase < 512) ? colbase : colbase - 512;
  floatx4 acc[4][4];
#pragma unroll
  for (int m = 0; m < 4; ++m)
#pragma unroll
    for (int n = 0; n < 4; ++n)
#pragma unroll
      for (int r = 0; r < 4; ++r) acc[m][n][r] = 0.f;
#pragma unroll
  for (int ks = 0; ks < K / 32; ++ks) {
    short8 af[4], bfr[4];
#pragma unroll
    for (int m = 0; m < 4; ++m)
      af[m] = *(const short8*)&As[(m * 16 + cc) * RS + ks * 32 + q * 8];
#pragma unroll
    for (int n = 0; n < 4; ++n)
      bfr[n] = *(const short8*)&Bp[(size_t)(cb + n * 16 + cc) * K + ks * 32 + q * 8];
#pragma unroll
    for (int m = 0; m < 4; ++m)
#pragma unroll
      for (int n = 0; n < 4; ++n)
        acc[m][n] = mfma16(af[m], bfr[n], acc[m][n]);
  }
#pragma unroll
  for (int n = 0; n < 4; ++n) {
    const int col = colbase + n * 16 + cc;
    const float bv = bf2f(biasp[cb + n * 16 + cc]);
#pragma unroll
    for (int m = 0; m < 4; ++m) {
      short4v zv;
#pragma unroll
      for (int r = 0; r < 4; ++r)
        zv[r] = (short)f2bf(acc[m][n][r] + bv);
      *(short4v*)&Z[(size_t)(t * 1024 + col) * 64 + m * 16 + q * 4] = zv;
    }
  }
}

// ---------------------------------------------------------------------------
// FC head: one wave per (t,b). Output dtype via flag (1 = f32, 0 = bf16).
// ---------------------------------------------------------------------------
__global__ __launch_bounds__(256) void fc_kernel(
    const unsigned short* __restrict__ ys,   // [n][256] bf16
    const unsigned short* __restrict__ fcw,  // [256]
    const unsigned short* __restrict__ fcb,  // [1]
    void* __restrict__ out, size_t out_off, int n,
    const int* __restrict__ flag)
{
  const int gw = (int)((blockIdx.x * 256 + threadIdx.x) >> 6);
  const int lane = threadIdx.x & 63;
  if (gw >= n) return;
  const unsigned short* rp = ys + (size_t)gw * 256 + lane * 4;
  float s = 0.f;
#pragma unroll
  for (int i = 0; i < 4; ++i) s += bf2f(rp[i]) * bf2f(fcw[lane * 4 + i]);
#pragma unroll
  for (int m = 32; m >= 1; m >>= 1) s += __shfl_xor(s, m, 64);
  if (lane == 0) {
    const float v = fsig(s + bf2f(fcb[0]));
    if (*flag) ((float*)out)[out_off + gw] = v;
    else       ((unsigned short*)out)[out_off + gw] = f2bf(v);
  }
}

extern "C" void kernel_launch(void* const* d_in, const int* in_sizes, int n_in,
                              void* d_out, int out_size, void* d_ws, size_t ws_size,
                              hipStream_t stream)
{
  (void)in_sizes; (void)n_in; (void)out_size;
  const int S = 4096;

  int* flag = (int*)d_ws;
  unsigned short* wbuf = (unsigned short*)((char*)d_ws + 256);
  static const int woff[14] = {0,      49152,  114688, 115200, 164352, 229888,
                               230400, 361472, 427008, 427520, 558592, 624128,
                               624640, 624896};
  const size_t wbuf_end = 256 + 1250304;  // bytes

  // Per-step bytes: Z0+Z1 bf16 2*131072 + ys0+ys1 2*32768 = 327680.
  // Fixed: wbuf_end + state 196608. C capped at 512.
  int C = 1;
  for (int cand = 512; cand >= 1; cand >>= 1) {
    size_t need = (size_t)cand * 327680 + wbuf_end + 196608;
    if (need <= ws_size) { C = cand; break; }
  }
  unsigned short* Z0 = (unsigned short*)((char*)d_ws + wbuf_end);  // C*65536 u16
  unsigned short* Z1 = Z0 + (size_t)C * 65536;
  unsigned short* ys0 = Z1 + (size_t)C * 65536;                    // C*16384 u16
  unsigned short* ys1 = ys0 + (size_t)C * 16384;
  float* c0 = (float*)(ys1 + (size_t)C * 16384);
  float* c1 = c0 + 16384;
  unsigned short* h0 = (unsigned short*)(c1 + 16384);
  unsigned short* h1 = h0 + 16384;

  const unsigned short* wih0f = wbuf + woff[0];
  const unsigned short* whh0f = wbuf + woff[1];
  const unsigned short* b0f   = wbuf + woff[2];
  const unsigned short* wih0b = wbuf + woff[3];
  const unsigned short* whh0b = wbuf + woff[4];
  const unsigned short* b0b   = wbuf + woff[5];
  const unsigned short* wih1f = wbuf + woff[6];
  const unsigned short* whh1f = wbuf + woff[7];
  const unsigned short* b1f   = wbuf + woff[8];
  const unsigned short* wih1b = wbuf + woff[9];
  const unsigned short* whh1b = wbuf + woff[10];
  const unsigned short* b1b   = wbuf + woff[11];
  const unsigned short* fcw   = wbuf + woff[12];
  const unsigned short* fcb   = wbuf + woff[13];

  detect_kernel<<<1, 256, 0, stream>>>((const unsigned short*)d_in[1], 49152, flag);
  convertw_kernel<<<614, 256, 0, stream>>>(
      d_in[1], d_in[2], d_in[3], d_in[4], d_in[5], d_in[6], d_in[7],
      d_in[8], d_in[9], d_in[10], d_in[11], d_in[12], d_in[13], d_in[14],
      wbuf, flag);

  const int nc = S / C;

  // prologue: chunk 0, layer 0
  gemm_kernel<96><<<dim3(C, 4), 256, 0, stream>>>(
      d_in[0], 0, 1, flag, wih0f, wih0b, b0f, b0b, Z0);
  rec_kernel<<<8, 512, 0, stream>>>(Z0, whh0f, whh0b, ys0, c0, h0, 1,
                                    Z0, whh0f, whh0b, ys0, c0, h0, 1, C);
  // pipelined middle: layer0 chunk c fused with layer1 chunk c-1
  for (int c = 1; c < nc; ++c) {
    gemm_kernel<96><<<dim3(C, 4), 256, 0, stream>>>(
        d_in[0], (size_t)c * C * 6144, 1, flag, wih0f, wih0b, b0f, b0b, Z0);
    gemm_kernel<256><<<dim3(C, 4), 256, 0, stream>>>(
        ys0, 0, 0, flag, wih1f, wih1b, b1f, b1b, Z1);
    rec_kernel<<<16, 512, 0, stream>>>(Z0, whh0f, whh0b, ys0, c0, h0, 0,
                                       Z1, whh1f, whh1b, ys1, c1, h1, (c == 1) ? 1 : 0, C);
    fc_kernel<<<C * 16, 256, 0, stream>>>(ys1, fcw, fcb, d_out,
                                          (size_t)(c - 1) * C * 64, C * 64, flag);
  }
  // epilogue: layer1 chunk nc-1
  gemm_kernel<256><<<dim3(C, 4), 256, 0, stream>>>(
      ys0, 0, 0, flag, wih1f, wih1b, b1f, b1b, Z1);
  rec_kernel<<<8, 512, 0, stream>>>(Z1, whh1f, whh1b, ys1, c1, h1, (nc == 1) ? 1 : 0,
                                    Z1, whh1f, whh1b, ys1, c1, h1, (nc == 1) ? 1 : 0, C);
  fc_kernel<<<C * 16, 256, 0, stream>>>(ys1, fcw, fcb, d_out,
                                        (size_t)(nc - 1) * C * 64, C * 64, flag);
}

// Round 9
// 6156.337 us; speedup vs baseline: 1.5448x; 1.3045x over previous
//
#include <hip/hip_runtime.h>
#include <stdint.h>

typedef short short8 __attribute__((ext_vector_type(8)));
typedef short short4v __attribute__((ext_vector_type(4)));
typedef float floatx4 __attribute__((ext_vector_type(4)));

#define LOG2E 1.44269504088896340736f

__device__ __forceinline__ float bf2f(unsigned short u) {
  unsigned v = ((unsigned)u) << 16;
  return __builtin_bit_cast(float, v);
}
__device__ __forceinline__ unsigned short f2bf(float f) {
  unsigned v = __builtin_bit_cast(unsigned, f);
  v += 0x7FFFu + ((v >> 16) & 1u);   // RNE
  return (unsigned short)(v >> 16);
}
__device__ __forceinline__ float fast_exp2(float x) {
#if __has_builtin(__builtin_amdgcn_exp2f)
  return __builtin_amdgcn_exp2f(x);
#else
  return exp2f(x);
#endif
}
__device__ __forceinline__ float fast_rcp(float x) {
#if __has_builtin(__builtin_amdgcn_rcpf)
  return __builtin_amdgcn_rcpf(x);
#else
  return 1.0f / x;
#endif
}
__device__ __forceinline__ float fsig(float x) {
  return fast_rcp(1.0f + fast_exp2(-LOG2E * x));
}
__device__ __forceinline__ float ftanh(float x) {
  float e = fast_exp2(2.0f * LOG2E * x);
  return 1.0f - 2.0f * fast_rcp(e + 1.0f);
}
__device__ __forceinline__ floatx4 mfma16(short8 a, short8 b, floatx4 c) {
  return __builtin_amdgcn_mfma_f32_16x16x32_bf16(a, b, c, 0, 0, 0);
}

// ---------------------------------------------------------------------------
// Dtype detection: if the buffer is float32, even-indexed u16 halves are float
// mantissa bits -> ~6% have bf16-exponent >= 0xF0. If bf16 (0.05-scaled
// weights), exponent <= 125 always -> 0 hits. flag: 1 = f32, 0 = bf16.
// ---------------------------------------------------------------------------
__global__ __launch_bounds__(256) void detect_kernel(
    const unsigned short* __restrict__ w, int n_u16, int* __restrict__ flag)
{
  __shared__ int cnt;
  if (threadIdx.x == 0) cnt = 0;
  __syncthreads();
  int local = 0;
  for (int i = threadIdx.x * 2; i < n_u16; i += 512) {  // even indices only
    unsigned e = (w[i] >> 7) & 0xFF;
    if (e >= 0xF0) local++;
  }
  atomicAdd(&cnt, local);
  __syncthreads();
  if (threadIdx.x == 0) *flag = (cnt > 64) ? 1 : 0;
}

// ---------------------------------------------------------------------------
// One merged kernel canonicalizing all 14 weight tensors to bf16 in ws.
// ---------------------------------------------------------------------------
__global__ __launch_bounds__(256) void convertw_kernel(
    const void* s0, const void* s1, const void* s2, const void* s3,
    const void* s4, const void* s5, const void* s6, const void* s7,
    const void* s8, const void* s9, const void* s10, const void* s11,
    const void* s12, const void* s13,
    unsigned short* __restrict__ wbuf, const int* __restrict__ flag)
{
  const void* srcs[14] = {s0, s1, s2, s3, s4, s5, s6, s7, s8, s9, s10, s11, s12, s13};
  const int woff[14] = {0,      49152,  114688, 115200, 164352, 229888,
                        230400, 361472, 427008, 427520, 558592, 624128,
                        624640, 624896};
  const int wlen[14] = {49152, 65536, 512, 49152, 65536, 512,
                        131072, 65536, 512, 131072, 65536, 512, 256, 1};
  int sb = 0, i = 0;
  for (i = 0; i < 14; ++i) {
    int nb = (wlen[i] + 1023) >> 10;
    if ((int)blockIdx.x < sb + nb) break;
    sb += nb;
  }
  const int base = ((int)blockIdx.x - sb) * 1024 + (int)threadIdx.x * 4;
  unsigned short* dst = wbuf + woff[i];
  if (*flag) {
    const float* s = (const float*)srcs[i];
#pragma unroll
    for (int j = 0; j < 4; ++j)
      if (base + j < wlen[i]) dst[base + j] = f2bf(s[base + j]);
  } else {
    const unsigned short* s = (const unsigned short*)srcs[i];
#pragma unroll
    for (int j = 0; j < 4; ++j)
      if (base + j < wlen[i]) dst[base + j] = s[base + j];
  }
}

// ---------------------------------------------------------------------------
// Fused recurrent kernel. Two layer contexts (a = L0 chunk c, b = L1 chunk
// c-1); blocks 0..7 -> a, 8..15 -> b. Block = dir*4 + batch-group (16 rows).
// Z bf16, BG-MAJOR layout: [t][dir][bg][512 cols][16 batches] -- each block's
// per-step read is ONE contiguous 16 KB slab (full 64-B lines, no granularity
// waste; the old batch-fastest layout fetched 2x its bytes from HBM).
// Z(t+1) prefetched at TOP of step t (pinned by sched_barrier); in-loop
// barrier drains LDS only.
// ---------------------------------------------------------------------------
__global__ __launch_bounds__(512, 2) void rec_kernel(
    const unsigned short* __restrict__ Za, const unsigned short* __restrict__ whhfa,
    const unsigned short* __restrict__ whhba,
    unsigned short* __restrict__ ysa, float* __restrict__ ca,
    unsigned short* __restrict__ ha, int inita,
    const unsigned short* __restrict__ Zb, const unsigned short* __restrict__ whhfb,
    const unsigned short* __restrict__ whhbb,
    unsigned short* __restrict__ ysb, float* __restrict__ cb,
    unsigned short* __restrict__ hb, int initb,
    int steps)
{
  __shared__ __align__(16) unsigned short hbuf[2][16][136];
  const int blk = blockIdx.x;
  const unsigned short* Z;
  const unsigned short* whhF;
  const unsigned short* whhB;
  unsigned short* ys;
  float* cst;
  unsigned short* hst;
  int init;
  if (blk < 8) {
    Z = Za; whhF = whhfa; whhB = whhba; ys = ysa; cst = ca; hst = ha; init = inita;
  } else {
    Z = Zb; whhF = whhfb; whhB = whhbb; ys = ysb; cst = cb; hst = hb; init = initb;
  }
  const int d = (blk >> 2) & 1, bg = blk & 3;
  const unsigned short* whh = d ? whhB : whhF;

  const int tid = threadIdx.x;
  const int w = tid >> 6, lane = tid & 63, q = lane >> 4, cc = lane & 15;
  const int u = w * 16 + cc;

  // Whh as MFMA B-fragments, register-resident (64 regs).
  short8 bfrag[4][4];
#pragma unroll
  for (int g = 0; g < 4; ++g)
#pragma unroll
    for (int k = 0; k < 4; ++k)
      bfrag[g][k] = *(const short8*)(whh + (size_t)(g * 128 + u) * 128 + k * 32 + q * 8);

  float creg[4];
  const int row = tid >> 5;          // 0..15
  const int col4 = (tid & 31) * 4;   // 0..124
  if (init) {
#pragma unroll
    for (int r = 0; r < 4; ++r) creg[r] = 0.f;
    short4v zz = {0, 0, 0, 0};
    *(short4v*)&hbuf[0][row][col4] = zz;
  } else {
#pragma unroll
    for (int r = 0; r < 4; ++r)
      creg[r] = cst[(size_t)(d * 64 + bg * 16 + q * 4 + r) * 128 + u];
    *(short4v*)&hbuf[0][row][col4] =
        *(const short4v*)(hst + (size_t)(d * 64 + bg * 16 + row) * 128 + col4);
  }
  __syncthreads();

  // BG-major: slab of this block = (d*4+bg); within slab: col*16 + batch.
  const size_t zbase = (size_t)(d * 4 + bg) * 8192 + u * 16 + q * 4;
  // prime: Z(0) in bf16 (per gate g: contiguous 8-B load)
  short4v zcur[4];
#pragma unroll
  for (int g = 0; g < 4; ++g)
    zcur[g] = *(const short4v*)(Z + zbase + g * 2048);

  for (int t = 0; t < steps; ++t) {
    const int cur = t & 1, nxt = cur ^ 1;
    // issue prefetch of Z(t+1) FIRST, pinned by a scheduling barrier
    const int tn = (t + 1 < steps) ? t + 1 : t;
    const unsigned short* ztn = Z + (size_t)tn * 65536 + zbase;
    short4v zpf[4];
#pragma unroll
    for (int g = 0; g < 4; ++g)
      zpf[g] = *(const short4v*)(ztn + g * 2048);
    __builtin_amdgcn_sched_barrier(0);

    // convert current z (bf16 -> fp32) into C-layout accumulators
    floatx4 acc[4];
#pragma unroll
    for (int g = 0; g < 4; ++g)
#pragma unroll
      for (int r = 0; r < 4; ++r)
        acc[g][r] = bf2f((unsigned short)zcur[g][r]);

    short8 af[4];
#pragma unroll
    for (int k = 0; k < 4; ++k)
      af[k] = *(const short8*)&hbuf[cur][cc][k * 32 + q * 8];
#pragma unroll
    for (int g = 0; g < 4; ++g)
#pragma unroll
      for (int k = 0; k < 4; ++k)
        acc[g] = mfma16(af[k], bfrag[g][k], acc[g]);
    // pointwise: lane owns (batch bg*16 + q*4+r, unit u), gates local
#pragma unroll
    for (int r = 0; r < 4; ++r) {
      float zi = acc[0][r], zf = acc[1][r], zg = acc[2][r], zo = acc[3][r];
      float cn = fsig(zf) * creg[r] + fsig(zi) * ftanh(zg);
      creg[r] = cn;
      hbuf[nxt][q * 4 + r][u] = f2bf(fsig(zo) * ftanh(cn));
    }
    // LDS-only barrier: drain ds ops, leave vmcnt (ys store + Z prefetch) alone
    asm volatile("s_waitcnt lgkmcnt(0)\n\ts_barrier" ::: "memory");
    unsigned short* yd = ys + (size_t)(t * 64 + bg * 16 + row) * 256 + d * 128 + col4;
    *(short4v*)yd = *(const short4v*)&hbuf[nxt][row][col4];
#pragma unroll
    for (int g = 0; g < 4; ++g) zcur[g] = zpf[g];
  }
#pragma unroll
  for (int r = 0; r < 4; ++r)
    cst[(size_t)(d * 64 + bg * 16 + q * 4 + r) * 128 + u] = creg[r];
  const int fin = steps & 1;
  *(short4v*)(hst + (size_t)(d * 64 + bg * 16 + row) * 128 + col4) =
      *(const short4v*)&hbuf[fin][row][col4];
}

// ---------------------------------------------------------------------------
// Input GEMM. A may be raw f32/bf16 input (dyn=1: dtype from *flag, converted
// during staging) or internal bf16 (dyn=0).
// Z output bf16 in BG-MAJOR layout: [t][dir][m(=bg)][512 cols][16 batches].
// ---------------------------------------------------------------------------
template <int K>
__global__ __launch_bounds__(256, 4) void gemm_kernel(
    const void* __restrict__ A, size_t a_off, int dyn,
    const int* __restrict__ flag,
    const unsigned short* __restrict__ Bf,   // [512][K]
    const unsigned short* __restrict__ Bb,
    const unsigned short* __restrict__ biasf,  // [512]
    const unsigned short* __restrict__ biasb,
    unsigned short* __restrict__ Z)          // [C][8][8192] bf16
{
  constexpr int RS = K + 8;
  __shared__ __align__(16) unsigned short As[64 * RS];
  const int t = blockIdx.x, ns = blockIdx.y;
  const int tid = threadIdx.x, w = tid >> 6, lane = tid & 63;
  const int q = lane >> 4, cc = lane & 15;
  constexpr int K8 = K / 8;
  const int use32 = dyn ? *flag : 0;   // wave-uniform branch
  if (use32) {
    const float* Arow = (const float*)A + a_off + (size_t)t * 64 * K;
    for (int ci = tid; ci < 64 * K8; ci += 256) {
      int r_ = ci / K8, c8 = ci % K8;
      const float* p = Arow + r_ * K + c8 * 8;
      floatx4 x0 = *(const floatx4*)p;
      floatx4 x1 = *(const floatx4*)(p + 4);
      short8 s;
#pragma unroll
      for (int j = 0; j < 4; ++j) {
        s[j] = (short)f2bf(x0[j]);
        s[4 + j] = (short)f2bf(x1[j]);
      }
      *(short8*)&As[r_ * RS + c8 * 8] = s;
    }
  } else {
    const unsigned short* Arow = (const unsigned short*)A + a_off + (size_t)t * 64 * K;
    for (int ci = tid; ci < 64 * K8; ci += 256) {
      int r_ = ci / K8, c8 = ci % K8;
      *(short8*)&As[r_ * RS + c8 * 8] = *(const short8*)&Arow[r_ * K + c8 * 8];
    }
  }
  __syncthreads();
  const int colbase = ns * 256 + w * 64;
  const unsigned short* Bp    = (colbase < 512) ? Bf : Bb;
  const unsigned short* biasp = (colbase < 512) ? biasf : biasb;
  const int cb = (colbase < 512) ? colbase : colbase - 512;
  const int dslab = (colbase < 512) ? 0 : 4;
  floatx4 acc[4][4];
#pragma unroll
  for (int m = 0; m < 4; ++m)
#pragma unroll
    for (int n = 0; n < 4; ++n)
#pragma unroll
      for (int r = 0; r < 4; ++r) acc[m][n][r] = 0.f;
#pragma unroll
  for (int ks = 0; ks < K / 32; ++ks) {
    short8 af[4], bfr[4];
#pragma unroll
    for (int m = 0; m < 4; ++m)
      af[m] = *(const short8*)&As[(m * 16 + cc) * RS + ks * 32 + q * 8];
#pragma unroll
    for (int n = 0; n < 4; ++n)
      bfr[n] = *(const short8*)&Bp[(size_t)(cb + n * 16 + cc) * K + ks * 32 + q * 8];
#pragma unroll
    for (int m = 0; m < 4; ++m)
#pragma unroll
      for (int n = 0; n < 4; ++n)
        acc[m][n] = mfma16(af[m], bfr[n], acc[m][n]);
  }
  // epilogue: m is the batch-group -> slab (dslab + m); within slab col*16+b
#pragma unroll
  for (int n = 0; n < 4; ++n) {
    const int col = cb + n * 16 + cc;
    const float bv = bf2f(biasp[col]);
#pragma unroll
    for (int m = 0; m < 4; ++m) {
      short4v zv;
#pragma unroll
      for (int r = 0; r < 4; ++r)
        zv[r] = (short)f2bf(acc[m][n][r] + bv);
      *(short4v*)&Z[((size_t)t * 8 + dslab + m) * 8192 + col * 16 + q * 4] = zv;
    }
  }
}

// ---------------------------------------------------------------------------
// FC head: one wave per (t,b). Output dtype via flag (1 = f32, 0 = bf16).
// ---------------------------------------------------------------------------
__global__ __launch_bounds__(256) void fc_kernel(
    const unsigned short* __restrict__ ys,   // [n][256] bf16
    const unsigned short* __restrict__ fcw,  // [256]
    const unsigned short* __restrict__ fcb,  // [1]
    void* __restrict__ out, size_t out_off, int n,
    const int* __restrict__ flag)
{
  const int gw = (int)((blockIdx.x * 256 + threadIdx.x) >> 6);
  const int lane = threadIdx.x & 63;
  if (gw >= n) return;
  const unsigned short* rp = ys + (size_t)gw * 256 + lane * 4;
  float s = 0.f;
#pragma unroll
  for (int i = 0; i < 4; ++i) s += bf2f(rp[i]) * bf2f(fcw[lane * 4 + i]);
#pragma unroll
  for (int m = 32; m >= 1; m >>= 1) s += __shfl_xor(s, m, 64);
  if (lane == 0) {
    const float v = fsig(s + bf2f(fcb[0]));
    if (*flag) ((float*)out)[out_off + gw] = v;
    else       ((unsigned short*)out)[out_off + gw] = f2bf(v);
  }
}

extern "C" void kernel_launch(void* const* d_in, const int* in_sizes, int n_in,
                              void* d_out, int out_size, void* d_ws, size_t ws_size,
                              hipStream_t stream)
{
  (void)in_sizes; (void)n_in; (void)out_size;
  const int S = 4096;

  int* flag = (int*)d_ws;
  unsigned short* wbuf = (unsigned short*)((char*)d_ws + 256);
  static const int woff[14] = {0,      49152,  114688, 115200, 164352, 229888,
                               230400, 361472, 427008, 427520, 558592, 624128,
                               624640, 624896};
  const size_t wbuf_end = 256 + 1250304;  // bytes

  // Per-step bytes: Z0+Z1 bf16 2*131072 + ys0+ys1 2*32768 = 327680.
  // Fixed: wbuf_end + state 196608. C capped at 256: chunk working set
  // (Z 67 MB + ys 33 MB + x 6 MB) stays L3-resident.
  int C = 1;
  for (int cand = 256; cand >= 1; cand >>= 1) {
    size_t need = (size_t)cand * 327680 + wbuf_end + 196608;
    if (need <= ws_size) { C = cand; break; }
  }
  unsigned short* Z0 = (unsigned short*)((char*)d_ws + wbuf_end);  // C*65536 u16
  unsigned short* Z1 = Z0 + (size_t)C * 65536;
  unsigned short* ys0 = Z1 + (size_t)C * 65536;                    // C*16384 u16
  unsigned short* ys1 = ys0 + (size_t)C * 16384;
  float* c0 = (float*)(ys1 + (size_t)C * 16384);
  float* c1 = c0 + 16384;
  unsigned short* h0 = (unsigned short*)(c1 + 16384);
  unsigned short* h1 = h0 + 16384;

  const unsigned short* wih0f = wbuf + woff[0];
  const unsigned short* whh0f = wbuf + woff[1];
  const unsigned short* b0f   = wbuf + woff[2];
  const unsigned short* wih0b = wbuf + woff[3];
  const unsigned short* whh0b = wbuf + woff[4];
  const unsigned short* b0b   = wbuf + woff[5];
  const unsigned short* wih1f = wbuf + woff[6];
  const unsigned short* whh1f = wbuf + woff[7];
  const unsigned short* b1f   = wbuf + woff[8];
  const unsigned short* wih1b = wbuf + woff[9];
  const unsigned short* whh1b = wbuf + woff[10];
  const unsigned short* b1b   = wbuf + woff[11];
  const unsigned short* fcw   = wbuf + woff[12];
  const unsigned short* fcb   = wbuf + woff[13];

  detect_kernel<<<1, 256, 0, stream>>>((const unsigned short*)d_in[1], 49152, flag);
  convertw_kernel<<<614, 256, 0, stream>>>(
      d_in[1], d_in[2], d_in[3], d_in[4], d_in[5], d_in[6], d_in[7],
      d_in[8], d_in[9], d_in[10], d_in[11], d_in[12], d_in[13], d_in[14],
      wbuf, flag);

  const int nc = S / C;

  // prologue: chunk 0, layer 0
  gemm_kernel<96><<<dim3(C, 4), 256, 0, stream>>>(
      d_in[0], 0, 1, flag, wih0f, wih0b, b0f, b0b, Z0);
  rec_kernel<<<8, 512, 0, stream>>>(Z0, whh0f, whh0b, ys0, c0, h0, 1,
                                    Z0, whh0f, whh0b, ys0, c0, h0, 1, C);
  // pipelined middle: layer0 chunk c fused with layer1 chunk c-1
  for (int c = 1; c < nc; ++c) {
    gemm_kernel<96><<<dim3(C, 4), 256, 0, stream>>>(
        d_in[0], (size_t)c * C * 6144, 1, flag, wih0f, wih0b, b0f, b0b, Z0);
    gemm_kernel<256><<<dim3(C, 4), 256, 0, stream>>>(
        ys0, 0, 0, flag, wih1f, wih1b, b1f, b1b, Z1);
    rec_kernel<<<16, 512, 0, stream>>>(Z0, whh0f, whh0b, ys0, c0, h0, 0,
                                       Z1, whh1f, whh1b, ys1, c1, h1, (c == 1) ? 1 : 0, C);
    fc_kernel<<<C * 16, 256, 0, stream>>>(ys1, fcw, fcb, d_out,
                                          (size_t)(c - 1) * C * 64, C * 64, flag);
  }
  // epilogue: layer1 chunk nc-1
  gemm_kernel<256><<<dim3(C, 4), 256, 0, stream>>>(
      ys0, 0, 0, flag, wih1f, wih1b, b1f, b1b, Z1);
  rec_kernel<<<8, 512, 0, stream>>>(Z1, whh1f, whh1b, ys1, c1, h1, (nc == 1) ? 1 : 0,
                                    Z1, whh1f, whh1b, ys1, c1, h1, (nc == 1) ? 1 : 0, C);
  fc_kernel<<<C * 16, 256, 0, stream>>>(ys1, fcw, fcb, d_out,
                                        (size_t)(nc - 1) * C * 64, C * 64, flag);
}

// Round 10
// 5247.081 us; speedup vs baseline: 1.8125x; 1.1733x over previous
//
#include <hip/hip_runtime.h>
#include <stdint.h>

typedef short short8 __attribute__((ext_vector_type(8)));
typedef short short4v __attribute__((ext_vector_type(4)));
typedef float floatx4 __attribute__((ext_vector_type(4)));

#define LOG2E 1.44269504088896340736f

__device__ __forceinline__ float bf2f(unsigned short u) {
  unsigned v = ((unsigned)u) << 16;
  return __builtin_bit_cast(float, v);
}
__device__ __forceinline__ unsigned short f2bf(float f) {
  unsigned v = __builtin_bit_cast(unsigned, f);
  v += 0x7FFFu + ((v >> 16) & 1u);   // RNE
  return (unsigned short)(v >> 16);
}
__device__ __forceinline__ float fast_exp2(float x) {
#if __has_builtin(__builtin_amdgcn_exp2f)
  return __builtin_amdgcn_exp2f(x);
#else
  return exp2f(x);
#endif
}
__device__ __forceinline__ float fast_rcp(float x) {
#if __has_builtin(__builtin_amdgcn_rcpf)
  return __builtin_amdgcn_rcpf(x);
#else
  return 1.0f / x;
#endif
}
__device__ __forceinline__ float fsig(float x) {
  return fast_rcp(1.0f + fast_exp2(-LOG2E * x));
}
__device__ __forceinline__ floatx4 mfma16(short8 a, short8 b, floatx4 c) {
  return __builtin_amdgcn_mfma_f32_16x16x32_bf16(a, b, c, 0, 0, 0);
}

// ---------------------------------------------------------------------------
// Dtype detection: f32 buffers have even-u16 "exponent" fields >= 0xF0 often;
// bf16 0.05-scaled weights never do. flag: 1 = f32, 0 = bf16.
// ---------------------------------------------------------------------------
__global__ __launch_bounds__(256) void detect_kernel(
    const unsigned short* __restrict__ w, int n_u16, int* __restrict__ flag)
{
  __shared__ int cnt;
  if (threadIdx.x == 0) cnt = 0;
  __syncthreads();
  int local = 0;
  for (int i = threadIdx.x * 2; i < n_u16; i += 512) {
    unsigned e = (w[i] >> 7) & 0xFF;
    if (e >= 0xF0) local++;
  }
  atomicAdd(&cnt, local);
  __syncthreads();
  if (threadIdx.x == 0) *flag = (cnt > 64) ? 1 : 0;
}

// ---------------------------------------------------------------------------
// One merged kernel canonicalizing all 14 weight tensors to bf16 in ws.
// ---------------------------------------------------------------------------
__global__ __launch_bounds__(256) void convertw_kernel(
    const void* s0, const void* s1, const void* s2, const void* s3,
    const void* s4, const void* s5, const void* s6, const void* s7,
    const void* s8, const void* s9, const void* s10, const void* s11,
    const void* s12, const void* s13,
    unsigned short* __restrict__ wbuf, const int* __restrict__ flag)
{
  const void* srcs[14] = {s0, s1, s2, s3, s4, s5, s6, s7, s8, s9, s10, s11, s12, s13};
  const int woff[14] = {0,      49152,  114688, 115200, 164352, 229888,
                        230400, 361472, 427008, 427520, 558592, 624128,
                        624640, 624896};
  const int wlen[14] = {49152, 65536, 512, 49152, 65536, 512,
                        131072, 65536, 512, 131072, 65536, 512, 256, 1};
  int sb = 0, i = 0;
  for (i = 0; i < 14; ++i) {
    int nb = (wlen[i] + 1023) >> 10;
    if ((int)blockIdx.x < sb + nb) break;
    sb += nb;
  }
  const int base = ((int)blockIdx.x - sb) * 1024 + (int)threadIdx.x * 4;
  unsigned short* dst = wbuf + woff[i];
  if (*flag) {
    const float* s = (const float*)srcs[i];
#pragma unroll
    for (int j = 0; j < 4; ++j)
      if (base + j < wlen[i]) dst[base + j] = f2bf(s[base + j]);
  } else {
    const unsigned short* s = (const unsigned short*)srcs[i];
#pragma unroll
    for (int j = 0; j < 4; ++j)
      if (base + j < wlen[i]) dst[base + j] = s[base + j];
  }
}

// ---------------------------------------------------------------------------
// Fused recurrent kernel. Two layer contexts (a = L0 chunk c, b = L1 chunk
// c-1); blocks 0..7 -> a, 8..15 -> b. Block = dir*4 + batch-group (16 rows).
// Z bf16, BG-MAJOR: [t][dir][bg][512 cols][16 batches] -- per-block per-step
// read is one contiguous 16 KB slab. Z(t+1) prefetched at TOP of step t.
// Pointwise uses fused rational sig*tanh forms: 5 exp + 3 rcp per pair
// (was 5 exp + 5 rcp) -- algebraically identical, verified round 7.
// ---------------------------------------------------------------------------
__global__ __launch_bounds__(512, 2) void rec_kernel(
    const unsigned short* __restrict__ Za, const unsigned short* __restrict__ whhfa,
    const unsigned short* __restrict__ whhba,
    unsigned short* __restrict__ ysa, float* __restrict__ ca,
    unsigned short* __restrict__ ha, int inita,
    const unsigned short* __restrict__ Zb, const unsigned short* __restrict__ whhfb,
    const unsigned short* __restrict__ whhbb,
    unsigned short* __restrict__ ysb, float* __restrict__ cb,
    unsigned short* __restrict__ hb, int initb,
    int steps)
{
  __shared__ __align__(16) unsigned short hbuf[2][16][136];
  const int blk = blockIdx.x;
  const unsigned short* Z;
  const unsigned short* whhF;
  const unsigned short* whhB;
  unsigned short* ys;
  float* cst;
  unsigned short* hst;
  int init;
  if (blk < 8) {
    Z = Za; whhF = whhfa; whhB = whhba; ys = ysa; cst = ca; hst = ha; init = inita;
  } else {
    Z = Zb; whhF = whhfb; whhB = whhbb; ys = ysb; cst = cb; hst = hb; init = initb;
  }
  const int d = (blk >> 2) & 1, bg = blk & 3;
  const unsigned short* whh = d ? whhB : whhF;

  const int tid = threadIdx.x;
  const int w = tid >> 6, lane = tid & 63, q = lane >> 4, cc = lane & 15;
  const int u = w * 16 + cc;

  // Whh as MFMA B-fragments, register-resident (64 regs).
  short8 bfrag[4][4];
#pragma unroll
  for (int g = 0; g < 4; ++g)
#pragma unroll
    for (int k = 0; k < 4; ++k)
      bfrag[g][k] = *(const short8*)(whh + (size_t)(g * 128 + u) * 128 + k * 32 + q * 8);

  float creg[4];
  const int row = tid >> 5;          // 0..15
  const int col4 = (tid & 31) * 4;   // 0..124
  if (init) {
#pragma unroll
    for (int r = 0; r < 4; ++r) creg[r] = 0.f;
    short4v zz = {0, 0, 0, 0};
    *(short4v*)&hbuf[0][row][col4] = zz;
  } else {
#pragma unroll
    for (int r = 0; r < 4; ++r)
      creg[r] = cst[(size_t)(d * 64 + bg * 16 + q * 4 + r) * 128 + u];
    *(short4v*)&hbuf[0][row][col4] =
        *(const short4v*)(hst + (size_t)(d * 64 + bg * 16 + row) * 128 + col4);
  }
  __syncthreads();

  // BG-major: slab of this block = (d*4+bg); within slab: col*16 + batch.
  const size_t zbase = (size_t)(d * 4 + bg) * 8192 + u * 16 + q * 4;
  short4v zcur[4];
#pragma unroll
  for (int g = 0; g < 4; ++g)
    zcur[g] = *(const short4v*)(Z + zbase + g * 2048);

  for (int t = 0; t < steps; ++t) {
    const int cur = t & 1, nxt = cur ^ 1;
    const int tn = (t + 1 < steps) ? t + 1 : t;
    const unsigned short* ztn = Z + (size_t)tn * 65536 + zbase;
    short4v zpf[4];
#pragma unroll
    for (int g = 0; g < 4; ++g)
      zpf[g] = *(const short4v*)(ztn + g * 2048);
    __builtin_amdgcn_sched_barrier(0);

    floatx4 acc[4];
#pragma unroll
    for (int g = 0; g < 4; ++g)
#pragma unroll
      for (int r = 0; r < 4; ++r)
        acc[g][r] = bf2f((unsigned short)zcur[g][r]);

    short8 af[4];
#pragma unroll
    for (int k = 0; k < 4; ++k)
      af[k] = *(const short8*)&hbuf[cur][cc][k * 32 + q * 8];
#pragma unroll
    for (int g = 0; g < 4; ++g)
#pragma unroll
      for (int k = 0; k < 4; ++k)
        acc[g] = mfma16(af[k], bfrag[g][k], acc[g]);

    // fused pointwise: lane owns (batch bg*16 + q*4+r, unit u)
    // sig(i)*tanh(g) = ei*(eg-1)/((1+ei)(1+eg)), eg = e^{2 zg}
#pragma unroll
    for (int r = 0; r < 4; ++r) {
      float zi = acc[0][r], zf = acc[1][r], zg = acc[2][r], zo = acc[3][r];
      float ei = fast_exp2(LOG2E * zi);
      float eg = fast_exp2((2.0f * LOG2E) * zg);
      float ef = fast_exp2(LOG2E * zf);
      float it = ei * (eg - 1.0f) * fast_rcp((1.0f + ei) * (1.0f + eg));
      float sf = ef * fast_rcp(1.0f + ef);
      float cn = sf * creg[r] + it;
      creg[r] = cn;
      float eo = fast_exp2(LOG2E * zo);
      float ec = fast_exp2(fminf((2.0f * LOG2E) * cn, 88.0f));
      float h = eo * (ec - 1.0f) * fast_rcp((1.0f + eo) * (1.0f + ec));
      hbuf[nxt][q * 4 + r][u] = f2bf(h);
    }
    // LDS-only barrier: drain ds ops, leave vmcnt (ys store + Z prefetch)
    asm volatile("s_waitcnt lgkmcnt(0)\n\ts_barrier" ::: "memory");
    unsigned short* yd = ys + (size_t)(t * 64 + bg * 16 + row) * 256 + d * 128 + col4;
    *(short4v*)yd = *(const short4v*)&hbuf[nxt][row][col4];
#pragma unroll
    for (int g = 0; g < 4; ++g) zcur[g] = zpf[g];
  }
#pragma unroll
  for (int r = 0; r < 4; ++r)
    cst[(size_t)(d * 64 + bg * 16 + q * 4 + r) * 128 + u] = creg[r];
  const int fin = steps & 1;
  *(short4v*)(hst + (size_t)(d * 64 + bg * 16 + row) * 128 + col4) =
      *(const short4v*)&hbuf[fin][row][col4];
}

// ---------------------------------------------------------------------------
// GEMM body (device fn). Z output bf16, BG-MAJOR [t][dir][m][512][16].
// ---------------------------------------------------------------------------
template <int K>
__device__ __forceinline__ void gemm_body(
    unsigned short* As, int t, int ns,
    const void* __restrict__ A, size_t a_off, int dyn,
    const int* __restrict__ flag,
    const unsigned short* __restrict__ Bf,
    const unsigned short* __restrict__ Bb,
    const unsigned short* __restrict__ biasf,
    const unsigned short* __restrict__ biasb,
    unsigned short* __restrict__ Z)
{
  constexpr int RS = K + 8;
  const int tid = threadIdx.x, w = tid >> 6, lane = tid & 63;
  const int q = lane >> 4, cc = lane & 15;
  constexpr int K8 = K / 8;
  const int use32 = dyn ? *flag : 0;   // wave-uniform branch
  if (use32) {
    const float* Arow = (const float*)A + a_off + (size_t)t * 64 * K;
    for (int ci = tid; ci < 64 * K8; ci += 256) {
      int r_ = ci / K8, c8 = ci % K8;
      const float* p = Arow + r_ * K + c8 * 8;
      floatx4 x0 = *(const floatx4*)p;
      floatx4 x1 = *(const floatx4*)(p + 4);
      short8 s;
#pragma unroll
      for (int j = 0; j < 4; ++j) {
        s[j] = (short)f2bf(x0[j]);
        s[4 + j] = (short)f2bf(x1[j]);
      }
      *(short8*)&As[r_ * RS + c8 * 8] = s;
    }
  } else {
    const unsigned short* Arow = (const unsigned short*)A + a_off + (size_t)t * 64 * K;
    for (int ci = tid; ci < 64 * K8; ci += 256) {
      int r_ = ci / K8, c8 = ci % K8;
      *(short8*)&As[r_ * RS + c8 * 8] = *(const short8*)&Arow[r_ * K + c8 * 8];
    }
  }
  __syncthreads();
  const int colbase = ns * 256 + w * 64;
  const unsigned short* Bp    = (colbase < 512) ? Bf : Bb;
  const unsigned short* biasp = (colbase < 512) ? biasf : biasb;
  const int cb = (colbase < 512) ? colbase : colbase - 512;
  const int dslab = (colbase < 512) ? 0 : 4;
  floatx4 acc[4][4];
#pragma unroll
  for (int m = 0; m < 4; ++m)
#pragma unroll
    for (int n = 0; n < 4; ++n)
#pragma unroll
      for (int r = 0; r < 4; ++r) acc[m][n][r] = 0.f;
#pragma unroll
  for (int ks = 0; ks < K / 32; ++ks) {
    short8 af[4], bfr[4];
#pragma unroll
    for (int m = 0; m < 4; ++m)
      af[m] = *(const short8*)&As[(m * 16 + cc) * RS + ks * 32 + q * 8];
#pragma unroll
    for (int n = 0; n < 4; ++n)
      bfr[n] = *(const short8*)&Bp[(size_t)(cb + n * 16 + cc) * K + ks * 32 + q * 8];
#pragma unroll
    for (int m = 0; m < 4; ++m)
#pragma unroll
      for (int n = 0; n < 4; ++n)
        acc[m][n] = mfma16(af[m], bfr[n], acc[m][n]);
  }
#pragma unroll
  for (int n = 0; n < 4; ++n) {
    const int col = cb + n * 16 + cc;
    const float bv = bf2f(biasp[col]);
#pragma unroll
    for (int m = 0; m < 4; ++m) {
      short4v zv;
#pragma unroll
      for (int r = 0; r < 4; ++r)
        zv[r] = (short)f2bf(acc[m][n][r] + bv);
      *(short4v*)&Z[((size_t)t * 8 + dslab + m) * 8192 + col * 16 + q * 4] = zv;
    }
  }
}

// ---------------------------------------------------------------------------
// FC body: block t computes 64 outputs for (t, b). 4 lanes (q) per output.
// ---------------------------------------------------------------------------
__device__ __forceinline__ void fc_body(
    int t, int fcn, const unsigned short* __restrict__ ys1,
    const unsigned short* __restrict__ fcw, const unsigned short* __restrict__ fcb,
    void* __restrict__ out, size_t out_off, const int* __restrict__ flag)
{
  if (fcn <= 0) return;
  const int tid = threadIdx.x;
  const int w = tid >> 6, lane = tid & 63;
  const int o = lane & 15, q = lane >> 4;
  const int b = w * 16 + o;
  const unsigned short* rp = ys1 + ((size_t)t * 64 + b) * 256 + q * 64;
  float s = 0.f;
#pragma unroll
  for (int j = 0; j < 16; ++j) {
    short4v v = *(const short4v*)(rp + j * 4);
    const unsigned short* wp = fcw + q * 64 + j * 4;
#pragma unroll
    for (int k = 0; k < 4; ++k) s += bf2f((unsigned short)v[k]) * bf2f(wp[k]);
  }
  s += __shfl_xor(s, 16, 64);
  s += __shfl_xor(s, 32, 64);
  if (q == 0) {
    const float v = fsig(s + bf2f(fcb[0]));
    const size_t idx = out_off + (size_t)t * 64 + b;
    if (*flag) ((float*)out)[idx] = v;
    else       ((unsigned short*)out)[idx] = f2bf(v);
  }
}

// ---------------------------------------------------------------------------
// Mega kernel: grid (C, 9). y 0..3 = gemm96(chunk c) [if do96],
// y 4..7 = gemm256 (ys0 -> Z1), y 8 = fc for chunk c-2 (fcn<=0 skips).
// ---------------------------------------------------------------------------
__global__ __launch_bounds__(256, 4) void mega_kernel(
    const void* __restrict__ x, size_t x_off, int do96,
    const int* __restrict__ flag,
    const unsigned short* __restrict__ ys0,
    const unsigned short* __restrict__ wih0f, const unsigned short* __restrict__ wih0b,
    const unsigned short* __restrict__ b0f, const unsigned short* __restrict__ b0b,
    const unsigned short* __restrict__ wih1f, const unsigned short* __restrict__ wih1b,
    const unsigned short* __restrict__ b1f, const unsigned short* __restrict__ b1b,
    unsigned short* __restrict__ Z0, unsigned short* __restrict__ Z1,
    const unsigned short* __restrict__ ys1,
    const unsigned short* __restrict__ fcw, const unsigned short* __restrict__ fcb,
    void* __restrict__ out, size_t fc_off, int fcn)
{
  __shared__ __align__(16) unsigned short As[64 * 264];
  const int y = blockIdx.y, t = blockIdx.x;
  if (y < 4) {
    if (!do96) return;
    gemm_body<96>(As, t, y, x, x_off, 1, flag, wih0f, wih0b, b0f, b0b, Z0);
  } else if (y < 8) {
    gemm_body<256>(As, t, y - 4, ys0, 0, 0, flag, wih1f, wih1b, b1f, b1b, Z1);
  } else {
    fc_body(t, fcn, ys1, fcw, fcb, out, fc_off, flag);
  }
}

// ---------------------------------------------------------------------------
// Standalone FC (final chunk only). One wave per (t,b).
// ---------------------------------------------------------------------------
__global__ __launch_bounds__(256) void fc_kernel(
    const unsigned short* __restrict__ ys,
    const unsigned short* __restrict__ fcw,
    const unsigned short* __restrict__ fcb,
    void* __restrict__ out, size_t out_off, int n,
    const int* __restrict__ flag)
{
  const int gw = (int)((blockIdx.x * 256 + threadIdx.x) >> 6);
  const int lane = threadIdx.x & 63;
  if (gw >= n) return;
  const unsigned short* rp = ys + (size_t)gw * 256 + lane * 4;
  float s = 0.f;
#pragma unroll
  for (int i = 0; i < 4; ++i) s += bf2f(rp[i]) * bf2f(fcw[lane * 4 + i]);
#pragma unroll
  for (int m = 32; m >= 1; m >>= 1) s += __shfl_xor(s, m, 64);
  if (lane == 0) {
    const float v = fsig(s + bf2f(fcb[0]));
    if (*flag) ((float*)out)[out_off + gw] = v;
    else       ((unsigned short*)out)[out_off + gw] = f2bf(v);
  }
}

extern "C" void kernel_launch(void* const* d_in, const int* in_sizes, int n_in,
                              void* d_out, int out_size, void* d_ws, size_t ws_size,
                              hipStream_t stream)
{
  (void)in_sizes; (void)n_in; (void)out_size;
  const int S = 4096;

  int* flag = (int*)d_ws;
  unsigned short* wbuf = (unsigned short*)((char*)d_ws + 256);
  static const int woff[14] = {0,      49152,  114688, 115200, 164352, 229888,
                               230400, 361472, 427008, 427520, 558592, 624128,
                               624640, 624896};
  const size_t wbuf_end = 256 + 1250304;  // bytes

  // Per-step: Z0+Z1 bf16 2*131072 + ys0+ys1 2*32768 = 327680 B.
  // C capped at 256: chunk working set (~100 MB) stays L3-resident.
  int C = 1;
  for (int cand = 256; cand >= 1; cand >>= 1) {
    size_t need = (size_t)cand * 327680 + wbuf_end + 196608;
    if (need <= ws_size) { C = cand; break; }
  }
  unsigned short* Z0 = (unsigned short*)((char*)d_ws + wbuf_end);  // C*65536 u16
  unsigned short* Z1 = Z0 + (size_t)C * 65536;
  unsigned short* ys0 = Z1 + (size_t)C * 65536;                    // C*16384 u16
  unsigned short* ys1 = ys0 + (size_t)C * 16384;
  float* c0 = (float*)(ys1 + (size_t)C * 16384);
  float* c1 = c0 + 16384;
  unsigned short* h0 = (unsigned short*)(c1 + 16384);
  unsigned short* h1 = h0 + 16384;

  const unsigned short* wih0f = wbuf + woff[0];
  const unsigned short* whh0f = wbuf + woff[1];
  const unsigned short* b0f   = wbuf + woff[2];
  const unsigned short* wih0b = wbuf + woff[3];
  const unsigned short* whh0b = wbuf + woff[4];
  const unsigned short* b0b   = wbuf + woff[5];
  const unsigned short* wih1f = wbuf + woff[6];
  const unsigned short* whh1f = wbuf + woff[7];
  const unsigned short* b1f   = wbuf + woff[8];
  const unsigned short* wih1b = wbuf + woff[9];
  const unsigned short* whh1b = wbuf + woff[10];
  const unsigned short* b1b   = wbuf + woff[11];
  const unsigned short* fcw   = wbuf + woff[12];
  const unsigned short* fcb   = wbuf + woff[13];

  detect_kernel<<<1, 256, 0, stream>>>((const unsigned short*)d_in[1], 49152, flag);
  convertw_kernel<<<614, 256, 0, stream>>>(
      d_in[1], d_in[2], d_in[3], d_in[4], d_in[5], d_in[6], d_in[7],
      d_in[8], d_in[9], d_in[10], d_in[11], d_in[12], d_in[13], d_in[14],
      wbuf, flag);

  const int nc = S / C;

  // prologue: mega(0) = gemm96(0) (+ harmless gemm256 on stale ys0), rec L0(0)
  mega_kernel<<<dim3(C, 9), 256, 0, stream>>>(
      d_in[0], 0, 1, flag, ys0,
      wih0f, wih0b, b0f, b0b, wih1f, wih1b, b1f, b1b,
      Z0, Z1, ys1, fcw, fcb, d_out, 0, 0);
  rec_kernel<<<8, 512, 0, stream>>>(Z0, whh0f, whh0b, ys0, c0, h0, 1,
                                    Z0, whh0f, whh0b, ys0, c0, h0, 1, C);
  // pipelined middle: mega(c) = gemm96(c) + gemm256(ys0 of c-1) + fc(c-2)
  for (int c = 1; c < nc; ++c) {
    const int fcn = (c >= 2) ? C * 64 : 0;
    mega_kernel<<<dim3(C, 9), 256, 0, stream>>>(
        d_in[0], (size_t)c * C * 6144, 1, flag, ys0,
        wih0f, wih0b, b0f, b0b, wih1f, wih1b, b1f, b1b,
        Z0, Z1, ys1, fcw, fcb, d_out, (size_t)(c - 2) * C * 64, fcn);
    rec_kernel<<<16, 512, 0, stream>>>(Z0, whh0f, whh0b, ys0, c0, h0, 0,
                                       Z1, whh1f, whh1b, ys1, c1, h1, (c == 1) ? 1 : 0, C);
  }
  // epilogue: gemm256(nc-1) + fc(nc-2) in one mega (do96=0), rec L1(nc-1), fc(nc-1)
  mega_kernel<<<dim3(C, 9), 256, 0, stream>>>(
      d_in[0], 0, 0, flag, ys0,
      wih0f, wih0b, b0f, b0b, wih1f, wih1b, b1f, b1b,
      Z0, Z1, ys1, fcw, fcb, d_out, (size_t)(nc - 2) * C * 64, C * 64);
  rec_kernel<<<8, 512, 0, stream>>>(Z1, whh1f, whh1b, ys1, c1, h1, (nc == 1) ? 1 : 0,
                                    Z1, whh1f, whh1b, ys1, c1, h1, (nc == 1) ? 1 : 0, C);
  fc_kernel<<<C * 16, 256, 0, stream>>>(ys1, fcw, fcb, d_out,
                                        (size_t)(nc - 1) * C * 64, C * 64, flag);
}